// Round 12
// baseline (355.503 us; speedup 1.0000x reference)
//
#include <hip/hip_runtime.h>
#include <hip/hip_fp16.h>
#include <math.h>

// Problem constants (B=8, S=2048, T=128)
#define S_LEN 2048
#define T_DIM 128
#define BM 128               // tokens per block (m-range)
#define TN 32                // output cols per block
#define NBLK 512             // (mb 0..127) x (tq 0..3); == 2 blocks/CU x 256 CUs
#define TOKR 132             // tokT2 row stride in f16

typedef _Float16 half8 __attribute__((ext_vector_type(8)));
typedef _Float16 half4 __attribute__((ext_vector_type(4)));
typedef float floatx16 __attribute__((ext_vector_type(16)));

// Fast exact tanh: 1 - 2/(1+e^{2x})
__device__ __forceinline__ float tanh_fast(float x) {
  return 1.0f - __fdividef(2.0f, 1.0f + __expf(2.0f * x));
}

// ---------------------------------------------------------------------------
// SINGLE fused kernel, 512 blocks x 512 threads (=2 blocks/CU, co-residency
// guaranteed: LDS 66.6KB<=80KB, __launch_bounds__(512,4) caps regs at 128).
//
// Phase A (each block, 1/512 share): convert W fp32 -> W16f fp16 fragments;
//   init out[b,i,:] = Sw*tanh(bc)+br; then RELEASE (threadfence + barrier +
//   atomicAdd(counter)).  [R7-validated cross-XCD release/acquire pattern]
// Overlap: stage tokT2 + h16 (W16f-independent) while producers finish.
// ACQUIRE: tid0 spins on device-scope counter==512, barrier, all-thread fence.
// Phase B: R11 main loop verbatim (N-split, XCD-pinned W16f quarters,
//   4-buffer distance-3 prefetch, kh-parity LDS reduction, inline scatter).
// v_mfma_f32_32x32x16_f16: A lane m=l&31, k=(l>>5)*8+j; B n=l&31 same k;
// C/D col=l&31, row=(r&3)+8*(r>>2)+4*(l>>5)   [m74/m101-verified]
// ---------------------------------------------------------------------------
__global__ __launch_bounds__(512, 4) void fused_kernel(
    const float* __restrict__ tok, const int* __restrict__ heads,
    const float* __restrict__ W, const float* __restrict__ b_comp,
    const float* __restrict__ w_red, const float* __restrict__ b_red,
    _Float16* __restrict__ W16f, int* __restrict__ counter,
    float* __restrict__ out) {
  __shared__ _Float16 tokT2[128 * TOKR];   // 33.8 KB
  __shared__ float red[2][128 * TN];       // 2 x 16 KB
  __shared__ float swred[8];

  const int tid = threadIdx.x;
  const int lane = tid & 63;
  const int kh = tid >> 6;   // wave = q-chunk of 16 (kc index)
  const int l31 = lane & 31;
  const int lh = lane >> 5;
  const int blk = blockIdx.x;
  const int tq = (blk >> 1) & 3;                    // t-quarter, bits{1,2}
  const int mb = ((blk >> 3) << 1) | (blk & 1);     // bits{0,3..8}
  const size_t tokbase = (size_t)mb * BM * T_DIM;

  // ==================== PHASE A: convert share + init share ====================
  {
    // Sw = sum(w_red): each thread one float4 (512*4 = 2048)
    const float4 wv = *(const float4*)(w_red + tid * 4);
    float part = wv.x + wv.y + wv.z + wv.w;
#pragma unroll
    for (int o = 32; o > 0; o >>= 1) part += __shfl_down(part, o, 64);
    if (lane == 0) swred[kh] = part;

    // convert: this block handles tasks blk*2 + (tid>>8) of 1024 (t,qh,it)
    {
      const int task = blk * 2 + (tid >> 8);
      const int t = task >> 3;
      const int qh = (task >> 2) & 1;
      const int it = task & 3;
      const int tc = t >> 5, tl = t & 31;
      const int tid8 = tid & 255;
      const int e8 = it * 256 + tid8;     // 0..1023 over [p(128)][q-chunk(8)]
      const int p = e8 >> 3;
      const int q = qh * 64 + (e8 & 7) * 8;
      const float* src = W + (size_t)t * 16384 + (size_t)p * 128 + q;
      const float4 v0 = *(const float4*)src;
      const float4 v1 = *(const float4*)(src + 4);
      half8 h;
      h[0] = (_Float16)v0.x; h[1] = (_Float16)v0.y;
      h[2] = (_Float16)v0.z; h[3] = (_Float16)v0.w;
      h[4] = (_Float16)v1.x; h[5] = (_Float16)v1.y;
      h[6] = (_Float16)v1.z; h[7] = (_Float16)v1.w;
      const int kc = q >> 4, lh2 = (q >> 3) & 1;
      *(half8*)(W16f + ((size_t)((p * 4 + tc) * 8 + kc)) * 512 + lh2 * 256 + tl * 8) = h;
    }

    __syncthreads();
    float Sw = 0.f;
#pragma unroll
    for (int w = 0; w < 8; ++w) Sw += swred[w];
    const float br = b_red[0];

    // init out: this block's 4096-float share (8 floats/thread, row-aligned)
    const size_t base = (size_t)blk * 4096 + (size_t)tid * 8;
    const int t0 = (int)(base & 127);
    float4 a, b;
    a.x = Sw * tanh_fast(b_comp[t0 + 0]) + br;
    a.y = Sw * tanh_fast(b_comp[t0 + 1]) + br;
    a.z = Sw * tanh_fast(b_comp[t0 + 2]) + br;
    a.w = Sw * tanh_fast(b_comp[t0 + 3]) + br;
    b.x = Sw * tanh_fast(b_comp[t0 + 4]) + br;
    b.y = Sw * tanh_fast(b_comp[t0 + 5]) + br;
    b.z = Sw * tanh_fast(b_comp[t0 + 6]) + br;
    b.w = Sw * tanh_fast(b_comp[t0 + 7]) + br;
    *(float4*)(out + base) = a;
    *(float4*)(out + base + 4) = b;
  }

  // ---- RELEASE: publish this block's W16f + out-init shares ----
  __threadfence();
  __syncthreads();
  if (tid == 0) atomicAdd(counter, 1);

  // ==================== overlap: stage tokT2 + h16 (no W16f dep) ====================
#pragma unroll
  for (int it = 0; it < 8; ++it) {
    const int f = it * 512 + tid;   // 0..4095 float4s over [m(128)][p4(32)]
    const int m = f >> 5;
    const int p0 = (f & 31) * 4;
    const float4 v = *(const float4*)(tok + tokbase + (size_t)m * 128 + p0);
    const int mi = (m & 31) * 4 + (m >> 5);
    tokT2[(p0 + 0) * TOKR + mi] = (_Float16)v.x;
    tokT2[(p0 + 1) * TOKR + mi] = (_Float16)v.y;
    tokT2[(p0 + 2) * TOKR + mi] = (_Float16)v.z;
    tokT2[(p0 + 3) * TOKR + mi] = (_Float16)v.w;
  }

  half8 h16[4];
#pragma unroll
  for (int mh = 0; mh < 4; ++mh) {
    const int m = mh * 32 + l31;
    const int q0 = kh * 16 + lh * 8;
    const float4 v0 = *(const float4*)(tok + tokbase + (size_t)m * 128 + q0);
    const float4 v1 = *(const float4*)(tok + tokbase + (size_t)m * 128 + q0 + 4);
    h16[mh][0] = (_Float16)tanh_fast(v0.x);
    h16[mh][1] = (_Float16)tanh_fast(v0.y);
    h16[mh][2] = (_Float16)tanh_fast(v0.z);
    h16[mh][3] = (_Float16)tanh_fast(v0.w);
    h16[mh][4] = (_Float16)tanh_fast(v1.x);
    h16[mh][5] = (_Float16)tanh_fast(v1.y);
    h16[mh][6] = (_Float16)tanh_fast(v1.z);
    h16[mh][7] = (_Float16)tanh_fast(v1.w);
  }

  // ---- ACQUIRE: wait for all 512 producer shares, then fence ----
  if (tid == 0) {
    while (__hip_atomic_load(counter, __ATOMIC_RELAXED,
                             __HIP_MEMORY_SCOPE_AGENT) < NBLK) {
      __builtin_amdgcn_s_sleep(8);
    }
  }
  __syncthreads();   // also covers tokT2-ready
  __threadfence();   // acquire: no stale W16f/out lines

  // ==================== PHASE B: R11 main loop ====================
  const int off0 = ((tq * 8 + kh) << 9) + lane * 8;

  floatx16 acc[4];  // [mh] -> 64 AGPRs
#pragma unroll
  for (int mh = 0; mh < 4; ++mh)
#pragma unroll
    for (int r = 0; r < 16; ++r) acc[mh][r] = 0.f;

  half8 bf0, bf1, bf2, bf3;
  half4 tk0, tk1, tk2, tk3;

  auto loadB = [&](half8& bf, int p) {
    bf = *(const half8*)(W16f + (size_t)p * 16384 + off0);
  };
  auto loadT = [&](half4& tk, int p) {
    tk = *(const half4*)(tokT2 + p * TOKR + l31 * 4);
  };

  auto compute = [&](half8 bf, half4 tk) {
    half8 a0 = h16[0] * tk[0];
    half8 a1 = h16[1] * tk[1];
    half8 a2 = h16[2] * tk[2];
    half8 a3 = h16[3] * tk[3];
    acc[0] = __builtin_amdgcn_mfma_f32_32x32x16_f16(a0, bf, acc[0], 0, 0, 0);
    acc[1] = __builtin_amdgcn_mfma_f32_32x32x16_f16(a1, bf, acc[1], 0, 0, 0);
    acc[2] = __builtin_amdgcn_mfma_f32_32x32x16_f16(a2, bf, acc[2], 0, 0, 0);
    acc[3] = __builtin_amdgcn_mfma_f32_32x32x16_f16(a3, bf, acc[3], 0, 0, 0);
  };

  // 4-buffer, distance-3 software pipeline over 128 p (no barriers).
  loadB(bf0, 0);  loadT(tk0, 0);
  loadB(bf1, 1);  loadT(tk1, 1);
  loadB(bf2, 2);  loadT(tk2, 2);
  for (int p = 0; p < 124; p += 4) {
    loadB(bf3, p + 3);  loadT(tk3, p + 3);
    compute(bf0, tk0);
    loadB(bf0, p + 4);  loadT(tk0, p + 4);
    compute(bf1, tk1);
    loadB(bf1, p + 5);  loadT(tk1, p + 5);
    compute(bf2, tk2);
    loadB(bf2, p + 6);  loadT(tk2, p + 6);
    compute(bf3, tk3);
  }
  loadB(bf3, 127);  loadT(tk3, 127);
  compute(bf0, tk0);
  compute(bf1, tk1);
  compute(bf2, tk2);
  compute(bf3, tk3);

  // ---- kh reduction: parity -> plane, 4 serial phases (2 waves/phase) ----
  __syncthreads();
  {
    float* R = &red[kh & 1][0];
    const int g = kh >> 1;
#pragma unroll
    for (int phase = 0; phase < 4; ++phase) {
      if (g == phase) {
#pragma unroll
        for (int mh = 0; mh < 4; ++mh)
#pragma unroll
          for (int r = 0; r < 16; ++r) {
            const int m_loc = (r & 3) + 8 * (r >> 2) + 4 * lh;
            const int addr = (mh * 32 + m_loc) * TN + l31;
            if (phase == 0) R[addr] = acc[mh][r];
            else            R[addr] += acc[mh][r];
          }
      }
      __syncthreads();
    }
  }

  // ---- inline scatter epilogue: 512 threads, 8 m's x 1 t each ----
  const int t_loc = tid & 31;
  const int mgrp = tid >> 5;
  const int t = tq * 32 + t_loc;
  const float bc = b_comp[t];
  const float tb = tanh_fast(bc);
#pragma unroll 4
  for (int mi = 0; mi < 8; ++mi) {
    const int m_loc = mi * 16 + mgrp;
    const int gm = mb * BM + m_loc;
    const int head = heads[gm];
    const float wr = w_red[gm & 2047];
    const float v = red[0][m_loc * TN + t_loc] + red[1][m_loc * TN + t_loc] + bc;
    atomicAdd(out + ((size_t)(gm >> 11) * S_LEN + head) * T_DIM + t,
              wr * (tanh_fast(v) - tb));
  }
}

// ---------------------------------------------------------------------------
extern "C" void kernel_launch(void* const* d_in, const int* in_sizes, int n_in,
                              void* d_out, int out_size, void* d_ws, size_t ws_size,
                              hipStream_t stream) {
  const float* tok    = (const float*)d_in[0];
  // d_in[1] = dep_embeddings: dead input (source bug), unused
  const int*   heads  = (const int*)d_in[2];
  const float* W      = (const float*)d_in[3];
  const float* b_comp = (const float*)d_in[4];
  const float* w_red  = (const float*)d_in[5];
  const float* b_red  = (const float*)d_in[6];
  float* out = (float*)d_out;

  // ws layout: W16f 4MB at 0 | counter at 12MB
  char* ws = (char*)d_ws;
  _Float16* W16f = (_Float16*)ws;
  int* counter   = (int*)(ws + (12u << 20));

  hipMemsetAsync(counter, 0, sizeof(int), stream);
  fused_kernel<<<NBLK, 512, 0, stream>>>(tok, heads, W, b_comp, w_red, b_red,
                                         W16f, counter, out);
}

// Round 13
// 155.681 us; speedup vs baseline: 2.2835x; 2.2835x over previous
//
#include <hip/hip_runtime.h>
#include <hip/hip_fp16.h>
#include <math.h>

// Problem constants (B=8, S=2048, T=128)
#define S_LEN 2048
#define T_DIM 128
#define BM 64                // tokens per block (m-range)
#define TN 64                // output cols per block
#define NBLK 512             // (mb 0..255) x (th 0..1); th on bit1 -> XCD-pinned
#define TOKR 66              // tokT2 row stride in f16 (132 B)

typedef _Float16 half8 __attribute__((ext_vector_type(8)));
typedef _Float16 half2t __attribute__((ext_vector_type(2)));
typedef float floatx16 __attribute__((ext_vector_type(16)));

// Fast exact tanh: 1 - 2/(1+e^{2x})
__device__ __forceinline__ float tanh_fast(float x) {
  return 1.0f - __fdividef(2.0f, 1.0f + __expf(2.0f * x));
}

// ---------------------------------------------------------------------------
// Kernel A (grid 3072x256): fused prep (unchanged from R11):
//  blocks 0..1023  : W fp32 [t][p][q] -> W16f fp16 MFMA-fragment order
//    W16f[((p*4 + tc)*8 + kc)*512 + lh2*256 + (t&31)*8 + j]
//  blocks 1024..3071: out[b,i,t] = sum(w_red)*tanh(b_comp[t]) + b_red
// ---------------------------------------------------------------------------
__global__ __launch_bounds__(256) void prep_kernel(
    const float* __restrict__ W, const float* __restrict__ w_red,
    const float* __restrict__ b_comp, const float* __restrict__ b_red,
    _Float16* __restrict__ W16f, float* __restrict__ out) {
  const int blk = blockIdx.x;
  const int tid = threadIdx.x;
  if (blk < 1024) {
    const int t = blk >> 3;
    const int qh = (blk >> 2) & 1;
    const int it = blk & 3;
    const int tc = t >> 5, tl = t & 31;
    const int e8 = it * 256 + tid;        // 0..1023 over [p(128)][q-chunk(8)]
    const int p = e8 >> 3;
    const int q = qh * 64 + (e8 & 7) * 8;
    const float* src = W + (size_t)t * 16384 + (size_t)p * 128 + q;
    const float4 v0 = *(const float4*)src;
    const float4 v1 = *(const float4*)(src + 4);
    half8 h;
    h[0] = (_Float16)v0.x; h[1] = (_Float16)v0.y;
    h[2] = (_Float16)v0.z; h[3] = (_Float16)v0.w;
    h[4] = (_Float16)v1.x; h[5] = (_Float16)v1.y;
    h[6] = (_Float16)v1.z; h[7] = (_Float16)v1.w;
    const int kc = q >> 4, lh2 = (q >> 3) & 1;
    *(half8*)(W16f + ((size_t)((p * 4 + tc) * 8 + kc)) * 512 + lh2 * 256 + tl * 8) = h;
  } else {
    __shared__ float red4[4];
    float part = 0.f;
#pragma unroll
    for (int i = 0; i < 8; ++i) part += w_red[tid * 8 + i];
#pragma unroll
    for (int off = 32; off > 0; off >>= 1) part += __shfl_down(part, off, 64);
    if ((tid & 63) == 0) red4[tid >> 6] = part;
    __syncthreads();
    const float Sw = red4[0] + red4[1] + red4[2] + red4[3];
    const float br = b_red[0];
    const size_t base = (size_t)(blk - 1024) * 1024 + (size_t)tid * 4;
    const int t0 = (int)(base & 127);
    float4 v;
    v.x = Sw * tanh_fast(b_comp[t0 + 0]) + br;
    v.y = Sw * tanh_fast(b_comp[t0 + 1]) + br;
    v.z = Sw * tanh_fast(b_comp[t0 + 2]) + br;
    v.w = Sw * tanh_fast(b_comp[t0 + 3]) + br;
    *(float4*)(out + base) = v;
  }
}

// ---------------------------------------------------------------------------
// Kernel B: MFMA main, BM=64 x TN=64 (A-construction amortized over 2 t-tiles
// per wave: 8 pk_mul feed 4 MFMA -> per-wave MFMA issue ceiling 44%->67%).
// 512 blocks: th = bit1 (CU-mates blk/blk+256 share th; XCD = blk&7 pinned to
// one 2MB W16f half). 8 waves = kh 0..7 (16-q chunk); each wave covers both
// m-tiles and both t-tiles -> zero B redundancy (16 KB/CU/p, shared).
// Barrier-free p-loop, 3-buffer distance-2 prefetch (B: 2x1KB coalesced;
// tk: one ds_read_b32 gives both mh values). acc = 2x2 floatx16 = 64 AGPRs.
// LDS 49KB -> 2 blocks/CU, 4 waves/SIMD.
// v_mfma_f32_32x32x16_f16: A lane m=l&31, k=(l>>5)*8+j; B n=l&31 same k;
// C/D col=l&31, row=(r&3)+8*(r>>2)+4*(l>>5)   [m74/m101-verified]
// ---------------------------------------------------------------------------
__global__ __launch_bounds__(512, 4) void main_kernel(
    const float* __restrict__ tok, const int* __restrict__ heads,
    const _Float16* __restrict__ W16f, const float* __restrict__ b_comp,
    const float* __restrict__ w_red, float* __restrict__ out) {
  __shared__ _Float16 tokT2[128 * TOKR];  // 16.9 KB: [p][(m&31)*2 + (m>>5)]
  __shared__ float red[2][BM * TN];       // 2 x 16 KB: kh-parity planes [m][t_loc]

  const int tid = threadIdx.x;
  const int lane = tid & 63;
  const int kh = tid >> 6;   // wave = q-chunk of 16 (kc index)
  const int l31 = lane & 31;
  const int lh = lane >> 5;
  const int blk = blockIdx.x;
  const int th = (blk >> 1) & 1;                    // t-half, bit1 (XCD-pinned)
  const int mb = ((blk >> 2) << 1) | (blk & 1);     // 0..255
  const size_t tokbase = (size_t)mb * BM * T_DIM;

  // ---- stage tokT2: coalesced float4 reads, transposed f16 writes ----
#pragma unroll
  for (int it = 0; it < 4; ++it) {
    const int f = it * 512 + tid;   // 0..2047 float4s over [m(64)][p4(32)]
    const int m = f >> 5;
    const int p0 = (f & 31) * 4;
    const float4 v = *(const float4*)(tok + tokbase + (size_t)m * 128 + p0);
    const int mi = (m & 31) * 2 + (m >> 5);
    tokT2[(p0 + 0) * TOKR + mi] = (_Float16)v.x;
    tokT2[(p0 + 1) * TOKR + mi] = (_Float16)v.y;
    tokT2[(p0 + 2) * TOKR + mi] = (_Float16)v.z;
    tokT2[(p0 + 3) * TOKR + mi] = (_Float16)v.w;
  }

  // ---- per-lane h fragments: h16[mh], q0 = kh*16 + lh*8 ----
  half8 h16[2];
#pragma unroll
  for (int mh = 0; mh < 2; ++mh) {
    const int m = mh * 32 + l31;
    const int q0 = kh * 16 + lh * 8;
    const float4 v0 = *(const float4*)(tok + tokbase + (size_t)m * 128 + q0);
    const float4 v1 = *(const float4*)(tok + tokbase + (size_t)m * 128 + q0 + 4);
    h16[mh][0] = (_Float16)tanh_fast(v0.x);
    h16[mh][1] = (_Float16)tanh_fast(v0.y);
    h16[mh][2] = (_Float16)tanh_fast(v0.z);
    h16[mh][3] = (_Float16)tanh_fast(v0.w);
    h16[mh][4] = (_Float16)tanh_fast(v1.x);
    h16[mh][5] = (_Float16)tanh_fast(v1.y);
    h16[mh][6] = (_Float16)tanh_fast(v1.z);
    h16[mh][7] = (_Float16)tanh_fast(v1.w);
  }
  __syncthreads();  // tokT2 ready; last barrier before the p-loop

  // Wave's B-fragment offsets: tc = th*2 + tt, kc = kh
  int off[2];
#pragma unroll
  for (int tt = 0; tt < 2; ++tt)
    off[tt] = (((th * 2 + tt) * 8 + kh) << 9) + lane * 8;

  floatx16 acc[2][2];  // [mh][tt] -> 64 AGPRs
#pragma unroll
  for (int mh = 0; mh < 2; ++mh)
#pragma unroll
    for (int tt = 0; tt < 2; ++tt)
#pragma unroll
      for (int r = 0; r < 16; ++r) acc[mh][tt][r] = 0.f;

  half8 bf0[2], bf1[2], bf2[2];
  half2t tk0, tk1, tk2;

  auto loadB = [&](half8 (&bf)[2], int p) {
    const _Float16* wp = W16f + (size_t)p * 16384;
    bf[0] = *(const half8*)(wp + off[0]);
    bf[1] = *(const half8*)(wp + off[1]);
  };
  auto loadT = [&](half2t& tk, int p) {
    tk = *(const half2t*)(tokT2 + p * TOKR + l31 * 2);
  };

  auto compute = [&](half8 (&bf)[2], half2t tk) {
    half8 a0 = h16[0] * tk[0];   // 4 v_pk_mul
    half8 a1 = h16[1] * tk[1];   // 4 v_pk_mul
    acc[0][0] = __builtin_amdgcn_mfma_f32_32x32x16_f16(a0, bf[0], acc[0][0], 0, 0, 0);
    acc[0][1] = __builtin_amdgcn_mfma_f32_32x32x16_f16(a0, bf[1], acc[0][1], 0, 0, 0);
    acc[1][0] = __builtin_amdgcn_mfma_f32_32x32x16_f16(a1, bf[0], acc[1][0], 0, 0, 0);
    acc[1][1] = __builtin_amdgcn_mfma_f32_32x32x16_f16(a1, bf[1], acc[1][1], 0, 0, 0);
  };

  // 3-buffer, distance-2 software pipeline over 128 p (no barriers).
  loadB(bf0, 0);  loadT(tk0, 0);
  loadB(bf1, 1);  loadT(tk1, 1);
  for (int p = 0; p < 126; p += 3) {
    loadB(bf2, p + 2);  loadT(tk2, p + 2);
    compute(bf0, tk0);
    loadB(bf0, p + 3);  loadT(tk0, p + 3);
    compute(bf1, tk1);
    loadB(bf1, p + 4);  loadT(tk1, p + 4);
    compute(bf2, tk2);
  }
  compute(bf0, tk0);  // p = 126
  compute(bf1, tk1);  // p = 127

  // ---- kh reduction: parity -> plane, 4 serial phases (2 waves/phase) ----
  __syncthreads();
  {
    float* R = &red[kh & 1][0];
    const int g = kh >> 1;
#pragma unroll
    for (int phase = 0; phase < 4; ++phase) {
      if (g == phase) {
#pragma unroll
        for (int mh = 0; mh < 2; ++mh)
#pragma unroll
          for (int tt = 0; tt < 2; ++tt) {
            const int t_loc = tt * 32 + l31;
#pragma unroll
            for (int r = 0; r < 16; ++r) {
              const int m_loc = mh * 32 + (r & 3) + 8 * (r >> 2) + 4 * lh;
              const int addr = m_loc * TN + t_loc;
              if (phase == 0) R[addr] = acc[mh][tt][r];
              else            R[addr] += acc[mh][tt][r];
            }
          }
      }
      __syncthreads();
    }
  }

  // ---- inline scatter epilogue: 512 threads, 8 m's x 1 t each ----
  const int t_loc = tid & 63;
  const int mgrp = tid >> 6;  // 0..7 (wave-uniform -> scalar heads/w_red loads)
  const int t = th * 64 + t_loc;
  const float bc = b_comp[t];
  const float tb = tanh_fast(bc);
#pragma unroll 4
  for (int mi = 0; mi < 8; ++mi) {
    const int m_loc = mi * 8 + mgrp;
    const int gm = mb * BM + m_loc;
    const int head = heads[gm];
    const float wr = w_red[gm & 2047];
    const float v = red[0][m_loc * TN + t_loc] + red[1][m_loc * TN + t_loc] + bc;
    atomicAdd(out + ((size_t)(gm >> 11) * S_LEN + head) * T_DIM + t,
              wr * (tanh_fast(v) - tb));
  }
}

// ---------------------------------------------------------------------------
extern "C" void kernel_launch(void* const* d_in, const int* in_sizes, int n_in,
                              void* d_out, int out_size, void* d_ws, size_t ws_size,
                              hipStream_t stream) {
  const float* tok    = (const float*)d_in[0];
  // d_in[1] = dep_embeddings: dead input (source bug), unused
  const int*   heads  = (const int*)d_in[2];
  const float* W      = (const float*)d_in[3];
  const float* b_comp = (const float*)d_in[4];
  const float* w_red  = (const float*)d_in[5];
  const float* b_red  = (const float*)d_in[6];
  float* out = (float*)d_out;

  _Float16* W16f = (_Float16*)d_ws;  // 4 MB, MFMA-fragment order

  prep_kernel<<<3072, 256, 0, stream>>>(W, w_red, b_comp, b_red, W16f, out);
  main_kernel<<<NBLK, 512, 0, stream>>>(tok, heads, W16f, b_comp, w_red, out);
}